// Round 8
// baseline (820.057 us; speedup 1.0000x reference)
//
#include <hip/hip_runtime.h>
#include <hip/hip_cooperative_groups.h>
#include <hip/hip_bf16.h>
#include <cstdint>
#include <cstddef>

namespace cg = cooperative_groups;

#define DFEAT 128
#define TROWS 48
#define APAD  132   // LDS row stride for A tile (f32), float4-aligned

// ---------------- conversion helpers ----------------

__device__ inline float4 bf4_to_f4(uint2 u) {
    float4 r;
    r.x = __uint_as_float(u.x << 16);
    r.y = __uint_as_float(u.x & 0xFFFF0000u);
    r.z = __uint_as_float(u.y << 16);
    r.w = __uint_as_float(u.y & 0xFFFF0000u);
    return r;
}

__device__ inline uint2 f4_to_bf4(float4 v) {
    __hip_bfloat16 b0 = __float2bfloat16(v.x);
    __hip_bfloat16 b1 = __float2bfloat16(v.y);
    __hip_bfloat16 b2 = __float2bfloat16(v.z);
    __hip_bfloat16 b3 = __float2bfloat16(v.w);
    unsigned short s0 = *reinterpret_cast<unsigned short*>(&b0);
    unsigned short s1 = *reinterpret_cast<unsigned short*>(&b1);
    unsigned short s2 = *reinterpret_cast<unsigned short*>(&b2);
    unsigned short s3 = *reinterpret_cast<unsigned short*>(&b3);
    uint2 u;
    u.x = (unsigned int)s0 | ((unsigned int)s1 << 16);
    u.y = (unsigned int)s2 | ((unsigned int)s3 << 16);
    return u;
}

// ---------------- fused aggregate + GEMM layer (device fn, block-stride over tiles) ----------------
// X bf16 pre-scaled by invs_out; row = 32 lanes x uint2 (256 B).
// jb/je = row_ptr[r] + toff[r>>8] (tile-partial scan + tile offset, no scan3 pass).

template <bool RELU, bool OUT_BF16>
__device__ __attribute__((always_inline)) void fused_layer(
    float At[TROWS][APAD],
    const unsigned short* __restrict__ X, const int* __restrict__ row_ptr,
    const int* __restrict__ toff, const int* __restrict__ col,
    const float* __restrict__ invs_out, const float* __restrict__ invs_in,
    const float* __restrict__ W, const float* __restrict__ bias,
    void* __restrict__ out, int N, int ntiles)
{
    const int tid = threadIdx.x;
    const uint2* X2 = reinterpret_cast<const uint2*>(X);

    for (int tile = blockIdx.x; tile < ntiles; tile += gridDim.x) {
        const int row0 = tile * TROWS;
        __syncthreads();   // previous iteration's GEMM reads of At complete

        // ---- aggregation: 8 groups of 32 lanes; lane -> feats lane*4..lane*4+3 ----
        {
            const int grp  = tid >> 5;
            const int lane = tid & 31;
            #pragma unroll
            for (int i = 0; i < 6; i++) {
                int r = grp * 6 + i;
                int grow = row0 + r;
                float4 acc = make_float4(0.f, 0.f, 0.f, 0.f);
                if (grow < N) {
                    int jb = row_ptr[grow]     + toff[grow >> 8];
                    int je = row_ptr[grow + 1] + toff[(grow + 1) >> 8];
                    int j = jb;
                    for (; j + 3 < je; j += 4) {
                        int s0 = col[j], s1 = col[j + 1], s2 = col[j + 2], s3 = col[j + 3];
                        float4 v0 = bf4_to_f4(X2[(size_t)s0 * 32 + lane]);
                        float4 v1 = bf4_to_f4(X2[(size_t)s1 * 32 + lane]);
                        float4 v2 = bf4_to_f4(X2[(size_t)s2 * 32 + lane]);
                        float4 v3 = bf4_to_f4(X2[(size_t)s3 * 32 + lane]);
                        acc.x += v0.x + v1.x + v2.x + v3.x;
                        acc.y += v0.y + v1.y + v2.y + v3.y;
                        acc.z += v0.z + v1.z + v2.z + v3.z;
                        acc.w += v0.w + v1.w + v2.w + v3.w;
                    }
                    for (; j + 1 < je; j += 2) {
                        int s0 = col[j], s1 = col[j + 1];
                        float4 v0 = bf4_to_f4(X2[(size_t)s0 * 32 + lane]);
                        float4 v1 = bf4_to_f4(X2[(size_t)s1 * 32 + lane]);
                        acc.x += v0.x + v1.x;
                        acc.y += v0.y + v1.y;
                        acc.z += v0.z + v1.z;
                        acc.w += v0.w + v1.w;
                    }
                    if (j < je) {
                        float4 v0 = bf4_to_f4(X2[(size_t)col[j] * 32 + lane]);
                        acc.x += v0.x; acc.y += v0.y; acc.z += v0.z; acc.w += v0.w;
                    }
                    float si = invs_in[grow];
                    acc.x *= si; acc.y *= si; acc.z *= si; acc.w *= si;
                }
                *reinterpret_cast<float4*>(&At[r][lane * 4]) = acc;
            }
        }
        __syncthreads();

        // ---- GEMM: thread -> 6 rows x 4 cols; A f32 from LDS; W f32 from L1/L2 ----
        const int r0 = (tid >> 5) * 6;
        const int c0 = (tid & 31) * 4;

        float acc[6][4];
        #pragma unroll
        for (int i = 0; i < 6; i++)
            #pragma unroll
            for (int j = 0; j < 4; j++) acc[i][j] = 0.0f;

        for (int k4 = 0; k4 < DFEAT; k4 += 4) {
            float4 a[6];
            #pragma unroll
            for (int i = 0; i < 6; i++)
                a[i] = *reinterpret_cast<const float4*>(&At[r0 + i][k4]);
            #pragma unroll
            for (int kk = 0; kk < 4; kk++) {
                float4 w = *reinterpret_cast<const float4*>(&W[(size_t)(k4 + kk) * DFEAT + c0]);
                #pragma unroll
                for (int i = 0; i < 6; i++) {
                    float av = (&a[i].x)[kk];
                    acc[i][0] += av * w.x;
                    acc[i][1] += av * w.y;
                    acc[i][2] += av * w.z;
                    acc[i][3] += av * w.w;
                }
            }
        }

        float4 bv = *reinterpret_cast<const float4*>(&bias[c0]);

        #pragma unroll
        for (int i = 0; i < 6; i++) {
            int grow = row0 + r0 + i;
            if (grow < N) {
                float4 o;
                o.x = acc[i][0] + bv.x;
                o.y = acc[i][1] + bv.y;
                o.z = acc[i][2] + bv.z;
                o.w = acc[i][3] + bv.w;
                if (RELU) {
                    o.x = fmaxf(o.x, 0.f); o.y = fmaxf(o.y, 0.f);
                    o.z = fmaxf(o.z, 0.f); o.w = fmaxf(o.w, 0.f);
                }
                if (OUT_BF16) {
                    float sc = invs_out[grow];   // pre-scale for next layer's aggregation
                    o.x *= sc; o.y *= sc; o.z *= sc; o.w *= sc;
                    unsigned short* ob = reinterpret_cast<unsigned short*>(out);
                    *reinterpret_cast<uint2*>(&ob[(size_t)grow * DFEAT + c0]) = f4_to_bf4(o);
                } else {
                    float* of = reinterpret_cast<float*>(out);
                    *reinterpret_cast<float4*>(&of[(size_t)grow * DFEAT + c0]) = o;
                }
            }
        }
    }
}

// ---------------- the single cooperative kernel ----------------

__global__ __launch_bounds__(256, 4) void k_all(
    const float* __restrict__ X, const int* __restrict__ src, const int* __restrict__ dst,
    const float* __restrict__ W1, const float* __restrict__ b1,
    const float* __restrict__ W2, const float* __restrict__ b2,
    float* __restrict__ out, unsigned short* __restrict__ Xs, unsigned short* __restrict__ h1,
    int* __restrict__ cnt_out, int* __restrict__ cnt_in,
    int* __restrict__ row_ptr, int* __restrict__ tsum, int* __restrict__ toff,
    float* __restrict__ invs_out, float* __restrict__ invs_in, int* __restrict__ col,
    int N, int E, int nb, int ntiles)
{
    cg::grid_group grid = cg::this_grid();
    __shared__ float At[TROWS][APAD];
    int* si = reinterpret_cast<int*>(&At[0][0]);   // 256-int scan buffer alias

    const int tid = threadIdx.x;
    const int gtid = blockIdx.x * 256 + tid;
    const int gstride = gridDim.x * 256;

    // ---- phase 0: zero degree counters (cnt_out, cnt_in adjacent) ----
    for (int i = gtid; i < 2 * N; i += gstride) cnt_out[i] = 0;
    grid.sync();

    // ---- phase 1: degree count ----
    for (int e = gtid; e < E; e += gstride) {
        atomicAdd(&cnt_out[src[e]], 1);
        atomicAdd(&cnt_in[dst[e]], 1);
    }
    grid.sync();

    // ---- phase 2: per-tile invs + partial scan + bf16 prescale ----
    for (int tile = blockIdx.x; tile < nb; tile += gridDim.x) {
        int i = tile * 256 + tid;
        int v = (i < N) ? cnt_in[i] : 0;
        if (i < N) {
            int co = cnt_out[i];
            invs_out[i] = rsqrtf((float)(co > 1 ? co : 1));
            invs_in[i]  = rsqrtf((float)(v  > 1 ? v  : 1));
            cnt_out[i] = 0;                      // becomes the fill cursor
        }
        __syncthreads();                         // si reuse across tiles
        si[tid] = v;
        __syncthreads();
        #pragma unroll
        for (int off = 1; off < 256; off <<= 1) {
            int x = (tid >= off) ? si[tid - off] : 0;
            __syncthreads();
            si[tid] += x;
            __syncthreads();
        }
        if (i <= N) row_ptr[i] = si[tid] - v;    // exclusive within tile (i==N covered)
        if (tid == 255) tsum[tile] = si[255];
        __syncthreads();

        // prescale this tile's rows: Xs[r,:] = bf16(X[r,:] * invs_out[r])
        const float4* X4 = reinterpret_cast<const float4*>(X);
        uint2* Xs2 = reinterpret_cast<uint2*>(Xs);
        int rbase = tile * 256;
        int rr = tid >> 3, q = tid & 7;
        #pragma unroll
        for (int rep = 0; rep < 8; rep++) {
            int row = rbase + rep * 32 + rr;
            if (row < N) {
                float sc = invs_out[row];
                size_t b = (size_t)row * 32;
                #pragma unroll
                for (int c = 0; c < 4; c++) {
                    float4 x = X4[b + q + c * 8];
                    x.x *= sc; x.y *= sc; x.z *= sc; x.w *= sc;
                    Xs2[b + q + c * 8] = f4_to_bf4(x);
                }
            }
        }
        __syncthreads();
    }
    grid.sync();

    // ---- phase 3: block 0 scans tile sums -> exclusive toff; toff[nb]=E ----
    if (blockIdx.x == 0) {
        int run = 0;
        int chunks = (nb + 255) / 256;
        for (int c = 0; c < chunks; c++) {
            int idx = c * 256 + tid;
            int v = (idx < nb) ? tsum[idx] : 0;
            __syncthreads();
            si[tid] = v;
            __syncthreads();
            #pragma unroll
            for (int off = 1; off < 256; off <<= 1) {
                int x = (tid >= off) ? si[tid - off] : 0;
                __syncthreads();
                si[tid] += x;
                __syncthreads();
            }
            if (idx < nb) toff[idx] = run + si[tid] - v;
            run += si[255];
        }
        if (tid == 0) {
            toff[nb] = run;                      // == E
            if ((N & 255) == 0) row_ptr[N] = 0;  // only case phase 2 didn't cover
        }
    }
    grid.sync();

    // ---- phase 4: counting-sort fill ----
    for (int e = gtid; e < E; e += gstride) {
        int d = dst[e];
        int pos = row_ptr[d] + toff[d >> 8] + atomicAdd(&cnt_out[d], 1);
        col[pos] = src[e];
    }
    grid.sync();

    // ---- phase 5: layer 1  Xs -> h1 = bf16(relu(agg@W1+b1) * invs_out) ----
    fused_layer<true, true>(At, Xs, row_ptr, toff, col, invs_out, invs_in,
                            W1, b1, (void*)h1, N, ntiles);
    grid.sync();

    // ---- phase 6: layer 2  h1 -> out (f32 final) ----
    fused_layer<false, false>(At, h1, row_ptr, toff, col, invs_out, invs_in,
                              W2, b2, (void*)out, N, ntiles);
}

// ---------------- launch ----------------

extern "C" void kernel_launch(void* const* d_in, const int* in_sizes, int n_in,
                              void* d_out, int out_size, void* d_ws, size_t ws_size,
                              hipStream_t stream) {
    // inputs: 0:t 1:h 2:src 3:dst 4:W1 5:b1 6:W2 7:b2 — float tensors are FLOAT32
    float* hbuf       = (float*)d_in[1];   // clobbered (h1 bf16); harness restores per launch
    const int* src    = (const int*)d_in[2];
    const int* dst    = (const int*)d_in[3];
    const float* W1   = (const float*)d_in[4];
    const float* b1   = (const float*)d_in[5];
    const float* W2   = (const float*)d_in[6];
    const float* b2   = (const float*)d_in[7];
    float* out        = (float*)d_out;

    int N = in_sizes[1] / DFEAT;
    int E = in_sizes[2];
    int nb = (N + 255) / 256;
    int ntiles = (N + TROWS - 1) / TROWS;

    // staging: Xs (bf16) in d_out's first half; h1 (bf16) in the input buffer
    unsigned short* Xs = reinterpret_cast<unsigned short*>(out);
    unsigned short* h1 = reinterpret_cast<unsigned short*>(hbuf);

    // workspace (4-byte words): CSR + norms ~= 4.6 MB
    int* wsi = (int*)d_ws;
    int*   cnt_out  = wsi;                        // N (later: fill cursor)
    int*   cnt_in   = wsi + (size_t)N;            // N
    int*   row_ptr  = wsi + 2 * (size_t)N;        // N+1
    int*   tsum     = wsi + 3 * (size_t)N + 1;    // nb
    int*   toff     = tsum + nb;                  // nb+1
    float* invs_out = (float*)(toff + nb + 1);    // N
    float* invs_in  = invs_out + N;               // N
    int*   col      = (int*)(invs_in + N);        // E

    // cooperative grid: blocks/CU from occupancy x CU count, capped (all loops grid-stride)
    int dev = 0;
    hipGetDevice(&dev);
    int numCU = 256;
    hipDeviceGetAttribute(&numCU, hipDeviceAttributeMultiprocessorCount, dev);
    int perCU = 0;
    hipOccupancyMaxActiveBlocksPerMultiprocessor(&perCU, (const void*)k_all, 256, 0);
    if (perCU < 1) perCU = 1;
    long long g = (long long)perCU * numCU;
    if (g > 1024) g = 1024;
    dim3 grid((unsigned)g), block(256);

    void* args[] = {
        (void*)&hbuf, (void*)&src, (void*)&dst,
        (void*)&W1, (void*)&b1, (void*)&W2, (void*)&b2,
        (void*)&out, (void*)&Xs, (void*)&h1,
        (void*)&cnt_out, (void*)&cnt_in, (void*)&row_ptr, (void*)&tsum, (void*)&toff,
        (void*)&invs_out, (void*)&invs_in, (void*)&col,
        (void*)&N, (void*)&E, (void*)&nb, (void*)&ntiles
    };
    hipLaunchCooperativeKernel((const void*)k_all, grid, block, args, 0, stream);
}

// Round 9
// 378.508 us; speedup vs baseline: 2.1666x; 2.1666x over previous
//
#include <hip/hip_runtime.h>
#include <hip/hip_bf16.h>
#include <cstdint>
#include <cstddef>

#define DFEAT 128
#define TROWS 48
#define APAD  132   // LDS row stride for A tile (f32), float4-aligned

// ---------------- conversion helpers ----------------

__device__ inline float4 bf4_to_f4(uint2 u) {
    float4 r;
    r.x = __uint_as_float(u.x << 16);
    r.y = __uint_as_float(u.x & 0xFFFF0000u);
    r.z = __uint_as_float(u.y << 16);
    r.w = __uint_as_float(u.y & 0xFFFF0000u);
    return r;
}

__device__ inline uint2 f4_to_bf4(float4 v) {
    __hip_bfloat16 b0 = __float2bfloat16(v.x);
    __hip_bfloat16 b1 = __float2bfloat16(v.y);
    __hip_bfloat16 b2 = __float2bfloat16(v.z);
    __hip_bfloat16 b3 = __float2bfloat16(v.w);
    unsigned short s0 = *reinterpret_cast<unsigned short*>(&b0);
    unsigned short s1 = *reinterpret_cast<unsigned short*>(&b1);
    unsigned short s2 = *reinterpret_cast<unsigned short*>(&b2);
    unsigned short s3 = *reinterpret_cast<unsigned short*>(&b3);
    uint2 u;
    u.x = (unsigned int)s0 | ((unsigned int)s1 << 16);
    u.y = (unsigned int)s2 | ((unsigned int)s3 << 16);
    return u;
}

// ---------------- CSR build ----------------

__global__ void k_count(const int* __restrict__ src, const int* __restrict__ dst,
                        int* __restrict__ cnt_out, int* __restrict__ cnt_in, int E) {
    int e = blockIdx.x * blockDim.x + threadIdx.x;
    if (e < E) {
        atomicAdd(&cnt_out[src[e]], 1);
        atomicAdd(&cnt_in[dst[e]], 1);
    }
}

// k_prep: per-256-node tile —
//   (a) invs from counts, reset cnt_out (fill cursor)
//   (b) tile-local exclusive scan of cnt_in -> row_ptr (+ row_ptr[N] if N interior)
//   (c) prescale: Xs[i,:] = bf16( X[i,:] * invs_out[i] )
__global__ __launch_bounds__(256) void k_prep(
    int* __restrict__ cnt_out, const int* __restrict__ cnt_in,
    float* __restrict__ invs_out, float* __restrict__ invs_in,
    int* __restrict__ row_ptr, int* __restrict__ tsum,
    const float* __restrict__ X, unsigned short* __restrict__ Xs, int N)
{
    __shared__ int s[256];
    const int t = threadIdx.x;
    const int i = blockIdx.x * 256 + t;

    int v = (i < N) ? cnt_in[i] : 0;
    if (i < N) {
        int co = cnt_out[i];
        invs_out[i] = rsqrtf((float)(co > 1 ? co : 1));
        invs_in[i]  = rsqrtf((float)(v  > 1 ? v  : 1));
        cnt_out[i] = 0;
    }
    s[t] = v;
    __syncthreads();
    #pragma unroll
    for (int off = 1; off < 256; off <<= 1) {
        int x = (t >= off) ? s[t - off] : 0;
        __syncthreads();
        s[t] += x;
        __syncthreads();
    }
    if (i < N) row_ptr[i] = s[t] - v;            // tile-local exclusive
    if (i + 1 == N) row_ptr[N] = s[t];           // N interior to last tile (N%256 != 0)
    if (t == 255) tsum[blockIdx.x] = s[255];
    __syncthreads();

    // prescale this tile's rows
    {
        const float4* X4 = reinterpret_cast<const float4*>(X);
        uint2* Xs2 = reinterpret_cast<uint2*>(Xs);
        int rbase = blockIdx.x * 256;
        int rr = t >> 3, q = t & 7;
        #pragma unroll
        for (int rep = 0; rep < 8; rep++) {
            int row = rbase + rep * 32 + rr;
            if (row < N) {
                float sc = invs_out[row];
                size_t b = (size_t)row * 32;
                #pragma unroll
                for (int c = 0; c < 4; c++) {
                    float4 x = X4[b + q + c * 8];
                    x.x *= sc; x.y *= sc; x.z *= sc; x.w *= sc;
                    Xs2[b + q + c * 8] = f4_to_bf4(x);
                }
            }
        }
    }
}

// scan of tile sums -> exclusive toff; toff[nb] = E; row_ptr[N]=0 if N%256==0
__global__ __launch_bounds__(1024) void k_scan2p(const int* __restrict__ tsum,
                                                 int* __restrict__ toff,
                                                 int* __restrict__ row_ptr, int nb, int N) {
    __shared__ int s[1024];
    int t = threadIdx.x;
    int v = (t < nb) ? tsum[t] : 0;
    s[t] = v;
    __syncthreads();
    #pragma unroll
    for (int off = 1; off < 1024; off <<= 1) {
        int x = (t >= off) ? s[t - off] : 0;
        __syncthreads();
        s[t] += x;
        __syncthreads();
    }
    if (t < nb) toff[t] = s[t] - v;              // exclusive
    if (t == nb - 1) toff[nb] = s[t];            // == E
    if (t == 0 && (N & 255) == 0) row_ptr[N] = 0;
}

__global__ void k_scan2s(const int* __restrict__ tsum, int* __restrict__ toff,
                         int* __restrict__ row_ptr, int nb, int N) {
    if (blockIdx.x == 0 && threadIdx.x == 0) {
        int run = 0;
        for (int b = 0; b < nb; b++) { toff[b] = run; run += tsum[b]; }
        toff[nb] = run;
        if ((N & 255) == 0) row_ptr[N] = 0;
    }
}

// counting-sort fill with folded tile offset
__global__ void k_fill(const int* __restrict__ src, const int* __restrict__ dst,
                       const int* __restrict__ row_ptr, const int* __restrict__ toff,
                       int* __restrict__ cur, int* __restrict__ col, int E) {
    int e = blockIdx.x * blockDim.x + threadIdx.x;
    if (e < E) {
        int d = dst[e];
        int pos = row_ptr[d] + toff[d >> 8] + atomicAdd(&cur[d], 1);
        col[pos] = src[e];
    }
}

// ---------------- fused aggregate (bf16 gather, pairwise-interleaved) + GEMM ----------------
// X bf16 pre-scaled by invs_out; row = 32 lanes x uint2 (256 B).
// 8 groups of 32 lanes; each group: 6 rows as 3 pairs, 2 rows interleaved -> 4 gathers in flight.

template <bool RELU, bool OUT_BF16>
__global__ __launch_bounds__(256, 6) void k_fused(
    const unsigned short* __restrict__ X, const int* __restrict__ row_ptr,
    const int* __restrict__ toff, const int* __restrict__ col,
    const float* __restrict__ invs_out, const float* __restrict__ invs_in,
    const float* __restrict__ W, const float* __restrict__ bias,
    void* __restrict__ out, int N)
{
    __shared__ float At[TROWS][APAD];

    const int tid  = threadIdx.x;
    const int row0 = blockIdx.x * TROWS;
    const uint2* X2 = reinterpret_cast<const uint2*>(X);

    // ---- aggregation ----
    {
        const int grp  = tid >> 5;
        const int lane = tid & 31;
        #pragma unroll
        for (int p = 0; p < 3; p++) {
            const int rA = grp * 6 + p * 2;
            const int rB = rA + 1;
            const int gA = row0 + rA;
            const int gB = row0 + rB;
            int jA = 0, eAe = 0, jB = 0, eBe = 0;
            if (gA < N) {
                jA  = row_ptr[gA] + toff[gA >> 8];
                eAe = row_ptr[gA + 1] + toff[(gA + 1) >> 8];
            }
            if (gB < N) {
                jB  = row_ptr[gB] + toff[gB >> 8];
                eBe = row_ptr[gB + 1] + toff[(gB + 1) >> 8];
            }
            float4 aA = make_float4(0.f, 0.f, 0.f, 0.f);
            float4 aB = make_float4(0.f, 0.f, 0.f, 0.f);

            // interleaved main loop: 2 neighbors from each row per iteration
            while (jA + 1 < eAe && jB + 1 < eBe) {
                int a0 = col[jA], a1 = col[jA + 1];
                int b0 = col[jB], b1 = col[jB + 1];
                float4 vA0 = bf4_to_f4(X2[(size_t)a0 * 32 + lane]);
                float4 vA1 = bf4_to_f4(X2[(size_t)a1 * 32 + lane]);
                float4 vB0 = bf4_to_f4(X2[(size_t)b0 * 32 + lane]);
                float4 vB1 = bf4_to_f4(X2[(size_t)b1 * 32 + lane]);
                aA.x += vA0.x + vA1.x; aA.y += vA0.y + vA1.y;
                aA.z += vA0.z + vA1.z; aA.w += vA0.w + vA1.w;
                aB.x += vB0.x + vB1.x; aB.y += vB0.y + vB1.y;
                aB.z += vB0.z + vB1.z; aB.w += vB0.w + vB1.w;
                jA += 2; jB += 2;
            }
            // drain A
            while (jA + 1 < eAe) {
                int a0 = col[jA], a1 = col[jA + 1];
                float4 v0 = bf4_to_f4(X2[(size_t)a0 * 32 + lane]);
                float4 v1 = bf4_to_f4(X2[(size_t)a1 * 32 + lane]);
                aA.x += v0.x + v1.x; aA.y += v0.y + v1.y;
                aA.z += v0.z + v1.z; aA.w += v0.w + v1.w;
                jA += 2;
            }
            if (jA < eAe) {
                float4 v0 = bf4_to_f4(X2[(size_t)col[jA] * 32 + lane]);
                aA.x += v0.x; aA.y += v0.y; aA.z += v0.z; aA.w += v0.w;
            }
            // drain B
            while (jB + 1 < eBe) {
                int b0 = col[jB], b1 = col[jB + 1];
                float4 v0 = bf4_to_f4(X2[(size_t)b0 * 32 + lane]);
                float4 v1 = bf4_to_f4(X2[(size_t)b1 * 32 + lane]);
                aB.x += v0.x + v1.x; aB.y += v0.y + v1.y;
                aB.z += v0.z + v1.z; aB.w += v0.w + v1.w;
                jB += 2;
            }
            if (jB < eBe) {
                float4 v0 = bf4_to_f4(X2[(size_t)col[jB] * 32 + lane]);
                aB.x += v0.x; aB.y += v0.y; aB.z += v0.z; aB.w += v0.w;
            }

            if (gA < N) {
                float s = invs_in[gA];
                aA.x *= s; aA.y *= s; aA.z *= s; aA.w *= s;
            }
            if (gB < N) {
                float s = invs_in[gB];
                aB.x *= s; aB.y *= s; aB.z *= s; aB.w *= s;
            }
            *reinterpret_cast<float4*>(&At[rA][lane * 4]) = aA;
            *reinterpret_cast<float4*>(&At[rB][lane * 4]) = aB;
        }
    }
    __syncthreads();

    // ---- GEMM: thread -> 6 rows x 4 cols; A f32 from LDS; W f32 from L1/L2 ----
    const int r0 = (tid >> 5) * 6;
    const int c0 = (tid & 31) * 4;

    float acc[6][4];
    #pragma unroll
    for (int i = 0; i < 6; i++)
        #pragma unroll
        for (int j = 0; j < 4; j++) acc[i][j] = 0.0f;

    for (int k4 = 0; k4 < DFEAT; k4 += 4) {
        float4 a[6];
        #pragma unroll
        for (int i = 0; i < 6; i++)
            a[i] = *reinterpret_cast<const float4*>(&At[r0 + i][k4]);
        #pragma unroll
        for (int kk = 0; kk < 4; kk++) {
            float4 w = *reinterpret_cast<const float4*>(&W[(size_t)(k4 + kk) * DFEAT + c0]);
            #pragma unroll
            for (int i = 0; i < 6; i++) {
                float av = (&a[i].x)[kk];
                acc[i][0] += av * w.x;
                acc[i][1] += av * w.y;
                acc[i][2] += av * w.z;
                acc[i][3] += av * w.w;
            }
        }
    }

    float4 bv = *reinterpret_cast<const float4*>(&bias[c0]);

    #pragma unroll
    for (int i = 0; i < 6; i++) {
        int grow = row0 + r0 + i;
        if (grow < N) {
            float4 o;
            o.x = acc[i][0] + bv.x;
            o.y = acc[i][1] + bv.y;
            o.z = acc[i][2] + bv.z;
            o.w = acc[i][3] + bv.w;
            if (RELU) {
                o.x = fmaxf(o.x, 0.f); o.y = fmaxf(o.y, 0.f);
                o.z = fmaxf(o.z, 0.f); o.w = fmaxf(o.w, 0.f);
            }
            if (OUT_BF16) {
                float sc = invs_out[grow];   // pre-scale for next layer's aggregation
                o.x *= sc; o.y *= sc; o.z *= sc; o.w *= sc;
                unsigned short* ob = reinterpret_cast<unsigned short*>(out);
                *reinterpret_cast<uint2*>(&ob[(size_t)grow * DFEAT + c0]) = f4_to_bf4(o);
            } else {
                float* of = reinterpret_cast<float*>(out);
                *reinterpret_cast<float4*>(&of[(size_t)grow * DFEAT + c0]) = o;
            }
        }
    }
}

// ---------------- launch ----------------

extern "C" void kernel_launch(void* const* d_in, const int* in_sizes, int n_in,
                              void* d_out, int out_size, void* d_ws, size_t ws_size,
                              hipStream_t stream) {
    // inputs: 0:t 1:h 2:src 3:dst 4:W1 5:b1 6:W2 7:b2 — float tensors are FLOAT32
    float* hbuf       = (float*)d_in[1];   // clobbered (h1 bf16); harness restores per launch
    const int* src    = (const int*)d_in[2];
    const int* dst    = (const int*)d_in[3];
    const float* W1   = (const float*)d_in[4];
    const float* b1   = (const float*)d_in[5];
    const float* W2   = (const float*)d_in[6];
    const float* b2   = (const float*)d_in[7];
    float* out        = (float*)d_out;

    const int N = in_sizes[1] / DFEAT;
    const int E = in_sizes[2];
    const int nb = (N + 255) / 256;

    // staging: Xs (bf16) in d_out's first half; h1 (bf16) in the input buffer
    unsigned short* Xs = reinterpret_cast<unsigned short*>(out);
    unsigned short* h1 = reinterpret_cast<unsigned short*>(hbuf);

    // workspace (4-byte words): CSR + norms ~= 4.6 MB
    int* wsi = (int*)d_ws;
    int*   cnt_out  = wsi;                        // N (later: fill cursor)
    int*   cnt_in   = wsi + (size_t)N;            // N
    int*   row_ptr  = wsi + 2 * (size_t)N;        // N+1 (tile-local exclusive)
    int*   tsum     = wsi + 3 * (size_t)N + 1;    // nb
    int*   toff     = tsum + nb;                  // nb+1
    float* invs_out = (float*)(toff + nb + 1);    // N
    float* invs_in  = invs_out + N;               // N
    int*   col      = (int*)(invs_in + N);        // E

    // 1. degrees
    hipMemsetAsync(cnt_out, 0, 2 * (size_t)N * sizeof(int), stream);
    k_count<<<(E + 255) / 256, 256, 0, stream>>>(src, dst, cnt_out, cnt_in, E);

    // 2. invs + tile scan + prescale, then toff scan, then fill
    k_prep<<<nb, 256, 0, stream>>>(cnt_out, cnt_in, invs_out, invs_in,
                                   row_ptr, tsum, hbuf, Xs, N);
    if (nb <= 1024)
        k_scan2p<<<1, 1024, 0, stream>>>(tsum, toff, row_ptr, nb, N);
    else
        k_scan2s<<<1, 64, 0, stream>>>(tsum, toff, row_ptr, nb, N);
    k_fill<<<(E + 255) / 256, 256, 0, stream>>>(src, dst, row_ptr, toff, cnt_out, col, E);

    // 3. layer 1: Xs(bf16, in d_out) -> h1 = bf16(relu(agg@W1+b1) * invs_out)
    const int gblocks = (N + TROWS - 1) / TROWS;
    k_fused<true, true><<<gblocks, 256, 0, stream>>>(
        Xs, row_ptr, toff, col, invs_out, invs_in, W1, b1, (void*)h1, N);

    // 4. layer 2: h1(bf16) -> d_out (f32 final; Xs region is dead)
    k_fused<false, false><<<gblocks, 256, 0, stream>>>(
        h1, row_ptr, toff, col, invs_out, invs_in, W2, b2, (void*)out, N);
}